// Round 3
// baseline (694.702 us; speedup 1.0000x reference)
//
#include <hip/hip_runtime.h>
#include <hip/hip_cooperative_groups.h>
#include <math.h>

namespace cg = cooperative_groups;

#define V   50257
#define H   1032
#define INW 2064
#define S   8192
#define NB  1024

// d_out flat layout (fp32): [output V][attn_context H][hidden H][attn_w S]
#define O_CTX  50257
#define O_HID  51289
#define O_ATTN 52321

// part1 (hnew-half of W_out dot) row boundaries done by end of each phase
#define R_B 14320
#define R_C 24560
#define R_D 38640

__device__ __forceinline__ float waveReduceSum(float x) {
#pragma unroll
  for (int off = 32; off > 0; off >>= 1) x += __shfl_down(x, off);
  return x;  // valid in lane 0
}

// dot of a 1032-float row (258 float4) against an LDS vector; reduced in lane 0
__device__ __forceinline__ float halfDot(const float4* __restrict__ row4,
                                         const float4* __restrict__ sh4, int lane) {
  float acc = 0.f;
  for (int i = lane; i < H / 4; i += 64) {
    float4 a = row4[i], c = sh4[i];
    acc += a.x * c.x + a.y * c.y + a.z * c.z + a.w * c.w;
  }
  return waveReduceSum(acc);
}

__global__ __launch_bounds__(256, 4) void uber_kernel(
    const int* __restrict__ word, const float* __restrict__ emb,
    const float* __restrict__ lc, const float* __restrict__ ph,
    const float* __restrict__ W_ih, const float* __restrict__ W_hh,
    const float* __restrict__ b_ih, const float* __restrict__ b_hh,
    const float* __restrict__ W_a, const float* __restrict__ enc,
    const float* __restrict__ W_out, const float* __restrict__ b_out,
    float* __restrict__ out, float* __restrict__ hnew, float* __restrict__ v,
    float* __restrict__ ctxv, float* __restrict__ scores,
    float* __restrict__ p1acc, float* __restrict__ partials) {
  cg::grid_group grid = cg::this_grid();
  __shared__ __align__(16) float sh[3104];
  __shared__ float redA[256], redB[256];
  __shared__ float wred[4][8];
  int b = blockIdx.x, t = threadIdx.x, wv = t >> 6, lane = t & 63;

  // ---------------- Phase A: GRU (block-per-row) + zero v/ctx ----------------
  {
    int w0 = word[0];
    for (int i = t; i < H; i += 256) {
      sh[i]       = emb[(size_t)w0 * H + i];   // x = [emb_row | lc]
      sh[H + i]   = lc[i];
      sh[INW + i] = ph[i];
    }
    __syncthreads();
    const float4* x4 = (const float4*)sh;
    const float4* h4 = (const float4*)(sh + INW);
    int nrows = (b < 8) ? 2 : 1;
    for (int rep = 0; rep < nrows; ++rep) {
      int j = (rep == 0) ? b : (NB + b);
      float p0 = 0, p1 = 0, p2 = 0, p3 = 0, p4 = 0, p5 = 0;
      const float4* wr = (const float4*)(W_ih + (size_t)j * INW);
      const float4* wz = (const float4*)(W_ih + (size_t)(H + j) * INW);
      const float4* wn = (const float4*)(W_ih + (size_t)(2 * H + j) * INW);
      for (int i = t; i < INW / 4; i += 256) {
        float4 xv = x4[i];
        float4 a = wr[i]; p0 += xv.x*a.x + xv.y*a.y + xv.z*a.z + xv.w*a.w;
        float4 c = wz[i]; p1 += xv.x*c.x + xv.y*c.y + xv.z*c.z + xv.w*c.w;
        float4 d = wn[i]; p2 += xv.x*d.x + xv.y*d.y + xv.z*d.z + xv.w*d.w;
      }
      const float4* ur = (const float4*)(W_hh + (size_t)j * H);
      const float4* uz = (const float4*)(W_hh + (size_t)(H + j) * H);
      const float4* un = (const float4*)(W_hh + (size_t)(2 * H + j) * H);
      for (int i = t; i < H / 4; i += 256) {
        float4 hv = h4[i];
        float4 a = ur[i]; p3 += hv.x*a.x + hv.y*a.y + hv.z*a.z + hv.w*a.w;
        float4 c = uz[i]; p4 += hv.x*c.x + hv.y*c.y + hv.z*c.z + hv.w*c.w;
        float4 d = un[i]; p5 += hv.x*d.x + hv.y*d.y + hv.z*d.z + hv.w*d.w;
      }
      p0 = waveReduceSum(p0); p1 = waveReduceSum(p1); p2 = waveReduceSum(p2);
      p3 = waveReduceSum(p3); p4 = waveReduceSum(p4); p5 = waveReduceSum(p5);
      if (lane == 0) {
        wred[wv][0] = p0; wred[wv][1] = p1; wred[wv][2] = p2;
        wred[wv][3] = p3; wred[wv][4] = p4; wred[wv][5] = p5;
      }
      __syncthreads();
      if (t == 0) {
        float s0 = 0, s1 = 0, s2 = 0, s3 = 0, s4 = 0, s5 = 0;
        for (int q = 0; q < 4; ++q) {
          s0 += wred[q][0]; s1 += wred[q][1]; s2 += wred[q][2];
          s3 += wred[q][3]; s4 += wred[q][4]; s5 += wred[q][5];
        }
        float gr = (s0 + b_ih[j]) + (s3 + b_hh[j]);
        float gz = (s1 + b_ih[H + j]) + (s4 + b_hh[H + j]);
        float r  = 1.f / (1.f + expf(-gr));
        float z  = 1.f / (1.f + expf(-gz));
        float n  = tanhf((s2 + b_ih[2 * H + j]) + r * (s5 + b_hh[2 * H + j]));
        float hv = (1.f - z) * n + z * ph[j];
        hnew[j] = hv;
        out[O_HID + j] = hv;
      }
      __syncthreads();
    }
    if (b == 8) for (int i = t; i < H; i += 256) v[i] = 0.f;
    if (b == 9) for (int i = t; i < H; i += 256) ctxv[i] = 0.f;
  }
  grid.sync();

  // ---------------- Phase B: va (129 blocks) || part1 rows [0, R_B) ----------
  if (b < 129) {
    int j0 = b * 8;
    float hn[8];
#pragma unroll
    for (int q = 0; q < 8; ++q) hn[q] = hnew[j0 + q];
    for (int k = t; k < H; k += 256) {
      float a = 0.f;
#pragma unroll
      for (int q = 0; q < 8; ++q) a += W_a[(size_t)(j0 + q) * H + k] * hn[q];
      atomicAdd(&v[k], a);
    }
  } else {
    for (int i = t; i < H; i += 256) sh[i] = hnew[i];
    __syncthreads();
    const float4* sh4 = (const float4*)sh;
    int w = (b - 129) * 4 + wv;  // [0, 3580)
#pragma unroll
    for (int q = 0; q < 4; ++q) {
      int r = w * 4 + q;  // [0, R_B)
      float acc = halfDot((const float4*)(W_out + (size_t)r * INW), sh4, lane);
      if (lane == 0) p1acc[r] = acc + b_out[r];
    }
  }
  grid.sync();

  // ---------------- Phase C: scores (512 blocks) || part1 [R_B, R_C) --------
  if (b < 512) {
    for (int i = t; i < H; i += 256) sh[i] = v[i];
    __syncthreads();
    const float4* sh4 = (const float4*)sh;
    int r0 = b * 16 + wv * 4;
#pragma unroll
    for (int q = 0; q < 4; ++q) {
      int r = r0 + q;  // [0, 8192)
      float acc = halfDot((const float4*)(enc + (size_t)r * H), sh4, lane);
      if (lane == 0) scores[r] = acc;
    }
  } else {
    for (int i = t; i < H; i += 256) sh[i] = hnew[i];
    __syncthreads();
    const float4* sh4 = (const float4*)sh;
    int w = (b - 512) * 4 + wv;  // [0, 2048)
#pragma unroll
    for (int q = 0; q < 5; ++q) {
      int r = R_B + w * 5 + q;  // [R_B, R_C)
      float acc = halfDot((const float4*)(W_out + (size_t)r * INW), sh4, lane);
      if (lane == 0) p1acc[r] = acc + b_out[r];
    }
  }
  grid.sync();

  // ------------- Phase D: ctx+softmax (320 blocks) || part1 [R_C, R_D) ------
  if (b < 320) {
    float m = -3.4e38f;
    for (int i = t; i < S; i += 256) m = fmaxf(m, scores[i]);
    redA[t] = m; __syncthreads();
    for (int off = 128; off; off >>= 1) {
      if (t < off) redA[t] = fmaxf(redA[t], redA[t + off]);
      __syncthreads();
    }
    m = redA[0]; __syncthreads();
    float s = 0.f;
    for (int i = t; i < S; i += 256) s += expf(scores[i] - m);
    redA[t] = s; __syncthreads();
    for (int off = 128; off; off >>= 1) {
      if (t < off) redA[t] += redA[t + off];
      __syncthreads();
    }
    float inv = 1.f / redA[0];
    int ct = b % 5, chunk = b / 5;
    int s0 = chunk * 128;
    if (t < 128) sh[t] = expf(scores[s0 + t] - m) * inv;
    __syncthreads();
    if (ct == 0 && t < 128) out[O_ATTN + s0 + t] = sh[t];
    int k = ct * 256 + t;
    if (k < H) {
      float acc = 0.f;
      for (int si = 0; si < 128; ++si) acc += sh[si] * enc[(size_t)(s0 + si) * H + k];
      atomicAdd(&ctxv[k], acc);
    }
  } else {
    for (int i = t; i < H; i += 256) sh[i] = hnew[i];
    __syncthreads();
    const float4* sh4 = (const float4*)sh;
    int w = (b - 320) * 4 + wv;  // [0, 2816)
#pragma unroll
    for (int q = 0; q < 5; ++q) {
      int r = R_C + w * 5 + q;  // [R_C, R_D)
      float acc = halfDot((const float4*)(W_out + (size_t)r * INW), sh4, lane);
      if (lane == 0) p1acc[r] = acc + b_out[r];
    }
  }
  grid.sync();

  // ---------------- Phase E: finish logits + per-block lse partials ---------
  {
    for (int i = t; i < H; i += 256) { sh[i] = hnew[i]; sh[H + i] = ctxv[i]; }
    __syncthreads();
    if (b == 0) for (int i = t; i < H; i += 256) out[O_CTX + i] = sh[H + i];
    const float4* sh4 = (const float4*)sh;
    int gw = b * 4 + wv;  // [0, 4096)
    float lm = -3.4e38f, ls = 0.f;
    for (int r = gw; r < V; r += 4096) {
      const float4* row4 = (const float4*)(W_out + (size_t)r * INW);
      float val;
      if (r < R_D) {
        float acc = halfDot(row4 + H / 4, sh4 + H / 4, lane);
        val = p1acc[r] + acc;
      } else {
        float acc = 0.f;
        for (int i = lane; i < INW / 4; i += 64) {
          float4 a = row4[i], c = sh4[i];
          acc += a.x * c.x + a.y * c.y + a.z * c.z + a.w * c.w;
        }
        acc = waveReduceSum(acc);
        val = acc + b_out[r];
      }
      if (lane == 0) {
        out[r] = val;
        float nm = fmaxf(lm, val);
        ls = ls * expf(lm - nm) + expf(val - nm);
        lm = nm;
      }
    }
    if (lane == 0) { wred[wv][0] = lm; wred[wv][1] = ls; }
    __syncthreads();
    if (t == 0) {
      float m = wred[0][0], s = wred[0][1];
      for (int q = 1; q < 4; ++q) {
        float nm = fmaxf(m, wred[q][0]);
        s = s * expf(m - nm) + wred[q][1] * expf(wred[q][0] - nm);
        m = nm;
      }
      partials[2 * b] = m;
      partials[2 * b + 1] = s;
    }
  }
  grid.sync();

  // ---------------- Phase F: combine partials + subtract lse ----------------
  {
    float m = -3.4e38f, s = 0.f;
    for (int i = t; i < NB; i += 256) {
      float bm = partials[2 * i], bs = partials[2 * i + 1];
      float nm = fmaxf(m, bm);
      s = s * expf(m - nm) + bs * expf(bm - nm);
      m = nm;
    }
    redA[t] = m; redB[t] = s;
    __syncthreads();
    for (int off = 128; off; off >>= 1) {
      if (t < off) {
        float m2 = redA[t + off], s2 = redB[t + off];
        float nm = fmaxf(redA[t], m2);
        redB[t] = redB[t] * expf(redA[t] - nm) + s2 * expf(m2 - nm);
        redA[t] = nm;
      }
      __syncthreads();
    }
    float L = redA[0] + logf(redB[0]);
    int gid = b * 256 + t;
    if (gid < V) out[gid] -= L;
  }
}

extern "C" void kernel_launch(void* const* d_in, const int* in_sizes, int n_in,
                              void* d_out, int out_size, void* d_ws, size_t ws_size,
                              hipStream_t stream) {
  const int*   word  = (const int*)d_in[0];
  const float* lc    = (const float*)d_in[1];
  const float* ph    = (const float*)d_in[2];
  const float* enc   = (const float*)d_in[3];
  const float* emb   = (const float*)d_in[4];
  const float* W_ih  = (const float*)d_in[5];
  const float* W_hh  = (const float*)d_in[6];
  const float* b_ih  = (const float*)d_in[7];
  const float* b_hh  = (const float*)d_in[8];
  const float* W_a   = (const float*)d_in[9];
  // d_in[10] = b_a: unused — constant shift of all attention scores, cancels in softmax.
  const float* W_out = (const float*)d_in[11];
  const float* b_out = (const float*)d_in[12];
  float* out = (float*)d_out;
  float* ws  = (float*)d_ws;

  // ws layout (floats): hnew[1032] v[1032] ctx[1032] scores[8192] p1acc[50257] partials[2048]
  float* hnew     = ws;
  float* v        = ws + 1032;
  float* ctxv     = ws + 2064;
  float* scores   = ws + 3096;
  float* p1acc    = ws + 11288;
  float* partials = ws + 61545;

  void* args[] = {(void*)&word, (void*)&emb, (void*)&lc, (void*)&ph,
                  (void*)&W_ih, (void*)&W_hh, (void*)&b_ih, (void*)&b_hh,
                  (void*)&W_a, (void*)&enc, (void*)&W_out, (void*)&b_out,
                  (void*)&out, (void*)&hnew, (void*)&v, (void*)&ctxv,
                  (void*)&scores, (void*)&p1acc, (void*)&partials};
  hipLaunchCooperativeKernel((void*)uber_kernel, dim3(NB), dim3(256), args, 0, stream);
}

// Round 4
// 176.514 us; speedup vs baseline: 3.9357x; 3.9357x over previous
//
#include <hip/hip_runtime.h>
#include <math.h>

#define V  50257
#define H  1032
#define INW 2064
#define S  8192

// d_out flat layout (fp32): [output V][attn_context H][hidden H][attn_w S]
#define O_CTX  50257
#define O_HID  51289
#define O_ATTN 52321

#define LGRID 1571              // logits blocks; 16 row-groups each
#define NPART LGRID             // lse partial pairs

__device__ __forceinline__ float waveReduceSum(float v) {
#pragma unroll
  for (int off = 32; off > 0; off >>= 1) v += __shfl_down(v, off);
  return v;
}

__device__ __forceinline__ float qReduceSum(float v) {  // sum within 16-lane group
#pragma unroll
  for (int m = 8; m > 0; m >>= 1) v += __shfl_xor(v, m, 16);
  return v;  // all 16 lanes hold the sum
}

// K1: GRU cell. 258 blocks; wave w of block b owns gate-row j = b*4+w.
// Block 0 zeroes the v accumulator.
__global__ __launch_bounds__(256) void gru_kernel(
    const int* __restrict__ word, const float* __restrict__ emb,
    const float* __restrict__ lc, const float* __restrict__ ph,
    const float* __restrict__ W_ih, const float* __restrict__ W_hh,
    const float* __restrict__ b_ih, const float* __restrict__ b_hh,
    float* __restrict__ hnew, float* __restrict__ hid_out,
    float* __restrict__ v_acc) {
  int t = threadIdx.x, wave = t >> 6, lane = t & 63;
  if (blockIdx.x == 0) {
    for (int k = t; k < H; k += 256) v_acc[k] = 0.f;
  }
  int j = blockIdx.x * 4 + wave;  // 0..1031

  const float4* erow = (const float4*)(emb + (size_t)word[0] * H);
  const float4* lc4  = (const float4*)lc;
  const float4* ph4  = (const float4*)ph;

  const float4* wr = (const float4*)(W_ih + (size_t)j * INW);
  const float4* wz = (const float4*)(W_ih + (size_t)(H + j) * INW);
  const float4* wn = (const float4*)(W_ih + (size_t)(2 * H + j) * INW);
  float sir = 0.f, siz = 0.f, sin_ = 0.f;
  for (int i = lane; i < INW / 4; i += 64) {  // 516 float4
    float4 xv = (i < H / 4) ? erow[i] : lc4[i - H / 4];
    float4 a = wr[i]; sir  += xv.x * a.x + xv.y * a.y + xv.z * a.z + xv.w * a.w;
    float4 b = wz[i]; siz  += xv.x * b.x + xv.y * b.y + xv.z * b.z + xv.w * b.w;
    float4 c = wn[i]; sin_ += xv.x * c.x + xv.y * c.y + xv.z * c.z + xv.w * c.w;
  }
  const float4* ur = (const float4*)(W_hh + (size_t)j * H);
  const float4* uz = (const float4*)(W_hh + (size_t)(H + j) * H);
  const float4* un = (const float4*)(W_hh + (size_t)(2 * H + j) * H);
  float shr = 0.f, shz = 0.f, shn = 0.f;
  for (int i = lane; i < H / 4; i += 64) {  // 258 float4
    float4 hv = ph4[i];
    float4 a = ur[i]; shr += hv.x * a.x + hv.y * a.y + hv.z * a.z + hv.w * a.w;
    float4 b = uz[i]; shz += hv.x * b.x + hv.y * b.y + hv.z * b.z + hv.w * b.w;
    float4 c = un[i]; shn += hv.x * c.x + hv.y * c.y + hv.z * c.z + hv.w * c.w;
  }
  sir = waveReduceSum(sir); siz = waveReduceSum(siz); sin_ = waveReduceSum(sin_);
  shr = waveReduceSum(shr); shz = waveReduceSum(shz); shn = waveReduceSum(shn);
  if (lane == 0) {
    float gr = (sir + b_ih[j])         + (shr + b_hh[j]);
    float gz = (siz + b_ih[H + j])     + (shz + b_hh[H + j]);
    float r  = 1.f / (1.f + expf(-gr));
    float z  = 1.f / (1.f + expf(-gz));
    float n  = tanhf((sin_ + b_ih[2 * H + j]) + r * (shn + b_hh[2 * H + j]));
    float hv = (1.f - z) * n + z * ph[j];
    hnew[j] = hv;
    hid_out[j] = hv;
  }
}

// K2: v[k] = sum_j W_a[j][k] * hnew[j].  grid (5, 16). Also zeroes ctx (y==0 row).
__global__ __launch_bounds__(256) void va_kernel(
    const float* __restrict__ W_a, const float* __restrict__ hnew,
    float* __restrict__ v, float* __restrict__ ctx) {
  int k = blockIdx.x * 256 + threadIdx.x;
  if (k >= H) return;
  if (blockIdx.y == 0) ctx[k] = 0.f;
  int j0 = blockIdx.y * 65;
  int j1 = min(j0 + 65, H);
  float acc = 0.f;
  for (int j = j0; j < j1; ++j) acc += W_a[(size_t)j * H + k] * hnew[j];
  atomicAdd(&v[k], acc);
}

// K3: scores[s] = enc[s,:] . v   (b_a dropped: constant shift cancels in softmax)
// 16-lane group per row: 512 blocks x 16 groups = 8192 rows.
__global__ __launch_bounds__(256) void scores_kernel(
    const float* __restrict__ enc, const float* __restrict__ v,
    float* __restrict__ scores) {
  __shared__ __align__(16) float sv[H];
  int t = threadIdx.x;
  for (int i = t; i < H; i += 256) sv[i] = v[i];
  __syncthreads();
  int sub = t & 15;
  int s = blockIdx.x * 16 + (t >> 4);
  const float4* row = (const float4*)(enc + (size_t)s * H);
  const float4* v4  = (const float4*)sv;
  float acc = 0.f;
  for (int i = sub; i < H / 4; i += 16) {  // ~16 iters
    float4 a = row[i], b = v4[i];
    acc += a.x * b.x + a.y * b.y + a.z * b.z + a.w * b.w;
  }
  acc = qReduceSum(acc);
  if (sub == 0) scores[s] = acc;
}

// K4: ctx[k] = sum_s w[s]*enc[s][k], softmax recomputed per block (deterministic,
// scores L2-resident). grid (5, 128): x = 256-col tile, y = 64-row chunk.
// Col-tile 0 also writes attn weights to d_out.
__global__ __launch_bounds__(256) void ctx_kernel(
    const float* __restrict__ enc, const float* __restrict__ scores,
    float* __restrict__ ctx, float* __restrict__ attn_out) {
  __shared__ float red[256];
  __shared__ float wsh[64];
  int t = threadIdx.x;
  float m = -3.4e38f;
  for (int i = t; i < S; i += 256) m = fmaxf(m, scores[i]);
  red[t] = m; __syncthreads();
  for (int off = 128; off; off >>= 1) {
    if (t < off) red[t] = fmaxf(red[t], red[t + off]);
    __syncthreads();
  }
  m = red[0]; __syncthreads();
  float s = 0.f;
  for (int i = t; i < S; i += 256) s += expf(scores[i] - m);
  red[t] = s; __syncthreads();
  for (int off = 128; off; off >>= 1) {
    if (t < off) red[t] += red[t + off];
    __syncthreads();
  }
  float inv = 1.f / red[0];
  int s0 = blockIdx.y * 64;
  if (t < 64) wsh[t] = expf(scores[s0 + t] - m) * inv;
  __syncthreads();
  if (blockIdx.x == 0 && t < 64) attn_out[s0 + t] = wsh[t];
  int k = blockIdx.x * 256 + t;
  if (k < H) {
    float acc = 0.f;
    for (int si = 0; si < 64; ++si) acc += wsh[si] * enc[(size_t)(s0 + si) * H + k];
    atomicAdd(&ctx[k], acc);
  }
}

// K5: logits + per-block lse partials. 16-lane group per vocab row;
// LGRID blocks x 16 groups, each group ~2 rows (stride 16*LGRID).
// Block 0 also emits ctx to d_out.
__global__ __launch_bounds__(256) void logits_kernel(
    const float* __restrict__ hnew, const float* __restrict__ ctx,
    const float* __restrict__ W_out, const float* __restrict__ b_out,
    float* __restrict__ out, float* __restrict__ ctx_out,
    float* __restrict__ partials) {
  __shared__ __align__(16) float joined[INW];
  __shared__ float pm[16], psv[16];
  int t = threadIdx.x;
  for (int k = t; k < H; k += 256) {
    joined[k] = hnew[k];
    joined[H + k] = ctx[k];
  }
  if (blockIdx.x == 0) {
    for (int k = t; k < H; k += 256) ctx_out[k] = ctx[k];
  }
  __syncthreads();
  int sub = t & 15;
  int grp = t >> 4;                       // 0..15
  int gslot = blockIdx.x * 16 + grp;      // [0, 16*LGRID)
  const float4* j4 = (const float4*)joined;
  float lm = -3.4e38f, ls = 0.f;
  for (int r = gslot; r < V; r += 16 * LGRID) {
    const float4* row = (const float4*)(W_out + (size_t)r * INW);
    float acc = 0.f;
    for (int i = sub; i < INW / 4; i += 16) {  // ~32 iters
      float4 a = row[i], c = j4[i];
      acc += a.x * c.x + a.y * c.y + a.z * c.z + a.w * c.w;
    }
    acc = qReduceSum(acc);
    if (sub == 0) {
      float x = acc + b_out[r];
      out[r] = x;
      float nm = fmaxf(lm, x);
      ls = ls * expf(lm - nm) + expf(x - nm);
      lm = nm;
    }
  }
  if (sub == 0) { pm[grp] = lm; psv[grp] = ls; }
  __syncthreads();
  if (t == 0) {
    float m = pm[0], sb = psv[0];
    for (int q = 1; q < 16; ++q) {
      float nm = fmaxf(m, pm[q]);
      sb = sb * expf(m - nm) + psv[q] * expf(pm[q] - nm);
      m = nm;
    }
    partials[2 * blockIdx.x]     = m;
    partials[2 * blockIdx.x + 1] = sb;
  }
}

// K6: combine partials (redundantly per block, deterministic) and subtract lse.
__global__ __launch_bounds__(256) void apply_kernel(
    float* __restrict__ out, const float* __restrict__ partials) {
  __shared__ float mm[256], ssv[256];
  int t = threadIdx.x;
  float m = -3.4e38f, s = 0.f;
  for (int i = t; i < NPART; i += 256) {
    float bm = partials[2 * i], bs = partials[2 * i + 1];
    float nm = fmaxf(m, bm);
    s = s * expf(m - nm) + bs * expf(bm - nm);
    m = nm;
  }
  mm[t] = m; ssv[t] = s; __syncthreads();
  for (int off = 128; off; off >>= 1) {
    if (t < off) {
      float m2 = mm[t + off], s2 = ssv[t + off];
      float nm = fmaxf(mm[t], m2);
      ssv[t] = ssv[t] * expf(mm[t] - nm) + s2 * expf(m2 - nm);
      mm[t] = nm;
    }
    __syncthreads();
  }
  float L = mm[0] + logf(ssv[0]);
  int i = blockIdx.x * 256 + t;
  if (i < V) out[i] -= L;
}

extern "C" void kernel_launch(void* const* d_in, const int* in_sizes, int n_in,
                              void* d_out, int out_size, void* d_ws, size_t ws_size,
                              hipStream_t stream) {
  const int*   word  = (const int*)d_in[0];
  const float* lc    = (const float*)d_in[1];
  const float* ph    = (const float*)d_in[2];
  const float* enc   = (const float*)d_in[3];
  const float* emb   = (const float*)d_in[4];
  const float* W_ih  = (const float*)d_in[5];
  const float* W_hh  = (const float*)d_in[6];
  const float* b_ih  = (const float*)d_in[7];
  const float* b_hh  = (const float*)d_in[8];
  const float* W_a   = (const float*)d_in[9];
  // d_in[10] = b_a: unused — constant shift of all attention scores, cancels in softmax.
  const float* W_out = (const float*)d_in[11];
  const float* b_out = (const float*)d_in[12];
  float* out = (float*)d_out;
  float* ws  = (float*)d_ws;

  // ws layout (floats): hnew[1032] | v[1032] | scores[8192] | ctx[1032] | partials[2*LGRID]
  float* hnew     = ws;
  float* v        = ws + 1032;
  float* scores   = ws + 2064;
  float* ctx      = ws + 10256;
  float* partials = ws + 11288;

  gru_kernel<<<258, 256, 0, stream>>>(word, emb, lc, ph, W_ih, W_hh, b_ih, b_hh,
                                      hnew, out + O_HID, v);
  va_kernel<<<dim3(5, 16), 256, 0, stream>>>(W_a, hnew, v, ctx);
  scores_kernel<<<512, 256, 0, stream>>>(enc, v, scores);
  ctx_kernel<<<dim3(5, 128), 256, 0, stream>>>(enc, scores, ctx, out + O_ATTN);
  logits_kernel<<<LGRID, 256, 0, stream>>>(hnew, ctx, W_out, b_out, out,
                                           out + O_CTX, partials);
  apply_kernel<<<(V + 255) / 256, 256, 0, stream>>>(out, partials);
}